// Round 3
// baseline (1165.197 us; speedup 1.0000x reference)
//
#include <hip/hip_runtime.h>

#define B_ 1024
#define S_ 256
#define D_ 128
#define K_ 26

// ---------------- Kernel 1: emissions E[b][t][k] = dot(X[b][t], W[k]) ----------------
__global__ __launch_bounds__(256, 2) void emis_kernel(
    const float* __restrict__ X, const float* __restrict__ W, float* __restrict__ E)
{
  __shared__ float xt[64][132];
  const int tid = threadIdx.x;
  const int b   = blockIdx.x >> 2;
  const int r0  = (blockIdx.x & 3) << 6;

  {
    const float4* Xs = reinterpret_cast<const float4*>(X + ((size_t)b * S_ + r0) * D_);
#pragma unroll
    for (int it = 0; it < 8; ++it) {
      int i = it * 256 + tid;
      float4 v = Xs[i];
      int row = i >> 5, col = (i & 31) << 2;
      *reinterpret_cast<float4*>(&xt[row][col]) = v;
    }
  }
  __syncthreads();

  const int l = tid & 63;
  const int g = __builtin_amdgcn_readfirstlane(tid >> 6);
  const int k0 = (g < 2) ? 7 * g : 6 * g + 2;
  const int kn = (g < 2) ? 7 : 6;

  float acc[7][4];
#pragma unroll
  for (int kk = 0; kk < 7; ++kk)
#pragma unroll
    for (int c = 0; c < 4; ++c) acc[kk][c] = 0.f;

#pragma unroll
  for (int dc = 0; dc < 16; ++dc) {
    float4 a0 = *reinterpret_cast<const float4*>(&xt[l][dc * 8]);
    float4 a1 = *reinterpret_cast<const float4*>(&xt[l][dc * 8 + 4]);
    float xv[8] = {a0.x, a0.y, a0.z, a0.w, a1.x, a1.y, a1.z, a1.w};
#pragma unroll
    for (int kk = 0; kk < 7; ++kk) {
      int k = k0 + kk; k = (k > K_ - 1) ? (K_ - 1) : k;
      const float* wr = W + k * D_ + dc * 8;
#pragma unroll
      for (int dd = 0; dd < 8; ++dd)
        acc[kk][dd & 3] = fmaf(xv[dd], wr[dd], acc[kk][dd & 3]);
    }
  }

  float* eb = E + ((size_t)b * S_ + r0 + l) * K_ + k0;
#pragma unroll
  for (int kk = 0; kk < 7; ++kk)
    if (kk < kn)
      eb[kk] = (acc[kk][0] + acc[kk][1]) + (acc[kk][2] + acc[kk][3]);
}

// ---------------- Kernel 2: Viterbi recurrence + backtrack, one wave per chain --------
__global__ __launch_bounds__(64, 1) void viterbi_kernel(
    const float* __restrict__ E, const float* __restrict__ Tr, int* __restrict__ out)
{
  __shared__ __align__(16) float e_lds[S_ * K_];   // 26624 B
  __shared__ unsigned char bp[K_][260];            // bp[j][t]
  __shared__ unsigned char spec[K_][132];          // speculative lower-half paths
  __shared__ int path_s[S_];

  const int lane = threadIdx.x;
  const int jc   = (lane < K_) ? lane : (K_ - 1);  // state owned by this lane
  const int b    = blockIdx.x;

  // stage E[b]
  {
    const float4* src = reinterpret_cast<const float4*>(E + (size_t)b * (S_ * K_));
    float4* dst = reinterpret_cast<float4*>(e_lds);
#pragma unroll
    for (int it = 0; it < 26; ++it) dst[it * 64 + lane] = src[it * 64 + lane];
  }

  // full transition column for this lane's state: tc[i] = Tr[i][jc]
  float tc[K_];
#pragma unroll
  for (int i = 0; i < K_; ++i) tc[i] = Tr[i * K_ + jc];

  __syncthreads();

  float delta = e_lds[jc];                 // t = 0
  float ev_next = e_lds[K_ + jc];          // prefetch t = 1

#pragma unroll 2
  for (int t = 1; t < S_; ++t) {
    float ev = ev_next;
    if (t + 1 < S_) ev_next = e_lds[(t + 1) * K_ + jc];   // off critical path

    // broadcast delta[i] to all lanes via v_readlane (VALU pipe, no LDS latency)
    float v[K_]; int id[K_];
#pragma unroll
    for (int i = 0; i < K_; ++i) {
      float di = __int_as_float(__builtin_amdgcn_readlane(__float_as_int(delta), i));
      v[i]  = di + tc[i];
      id[i] = i;
    }
    // ordered tournament: left (lower index) preferred on ties -> first-max (jnp.argmax)
#pragma unroll
    for (int w = 1; w < 32; w <<= 1) {
#pragma unroll
      for (int i = 0; i + w < K_; i += 2 * w) {
        bool g = v[i + w] > v[i];
        v[i]  = g ? v[i + w] : v[i];
        id[i] = g ? id[i + w] : id[i];
      }
    }
    if (lane < K_) bp[lane][t] = (unsigned char)id[0];
    delta = v[0] + ev;                     // same op order as reference
  }

  // final first-argmax over delta[0..25] (uniform result on all lanes)
  int last;
  {
    float v[K_]; int id[K_];
#pragma unroll
    for (int i = 0; i < K_; ++i) {
      v[i]  = __int_as_float(__builtin_amdgcn_readlane(__float_as_int(delta), i));
      id[i] = i;
    }
#pragma unroll
    for (int w = 1; w < 32; w <<= 1) {
#pragma unroll
      for (int i = 0; i + w < K_; i += 2 * w) {
        bool g = v[i + w] > v[i];
        v[i]  = g ? v[i + w] : v[i];
        id[i] = g ? id[i + w] : id[i];
      }
    }
    last = id[0];
  }

  __syncthreads();

  // backtrack: real chain (lane 63) t=255..129 concurrently with 26 speculative
  // chains (lanes 0..25) covering t=128..1 for every possible state@128.
  {
    int c = (lane < K_) ? lane : last;
    for (int k = 0; k < 128; ++k) {
      int t = (lane < K_) ? (128 - k) : (255 - k);
      bool act = (lane < K_) || (lane == 63 && k <= 126);
      if (act) {
        c = bp[c][t];
        if (lane < K_) spec[lane][t - 1] = (unsigned char)c;
        else if (t >= 129) path_s[t - 1] = c;   // covers 128..254
      }
    }
  }
  __syncthreads();

  {
    int sstar = path_s[128];
#pragma unroll
    for (int q = 0; q < 2; ++q) {
      int t = q * 64 + lane;
      path_s[t] = (int)spec[sstar][t];
    }
    if (lane == 0) path_s[S_ - 1] = last;
  }
  __syncthreads();

  int* o = out + (size_t)b * S_;
#pragma unroll
  for (int q = 0; q < 4; ++q) o[q * 64 + lane] = path_s[q * 64 + lane];
}

extern "C" void kernel_launch(void* const* d_in, const int* in_sizes, int n_in,
                              void* d_out, int out_size, void* d_ws, size_t ws_size,
                              hipStream_t stream) {
  (void)in_sizes; (void)n_in; (void)out_size; (void)ws_size;
  const float* X  = (const float*)d_in[0];
  const float* W  = (const float*)d_in[1];
  const float* Tr = (const float*)d_in[2];
  float* E = (float*)d_ws;             // needs B*S*K*4 = 27,262,976 B of scratch
  int* outp = (int*)d_out;

  emis_kernel<<<B_ * 4, 256, 0, stream>>>(X, W, E);
  viterbi_kernel<<<B_, 64, 0, stream>>>(E, Tr, outp);
}

// Round 4
// 391.807 us; speedup vs baseline: 2.9739x; 2.9739x over previous
//
#include <hip/hip_runtime.h>

#define B_ 1024
#define S_ 256
#define D_ 128
#define K_ 26
#define CPB 8   // chains (waves) per block

// ---------------- Kernel 1: emissions E[b][t][k] = dot(X[b][t], W[k]) ----------------
__global__ __launch_bounds__(256, 2) void emis_kernel(
    const float* __restrict__ X, const float* __restrict__ W, float* __restrict__ E)
{
  __shared__ float xt[64][132];
  const int tid = threadIdx.x;
  const int b   = blockIdx.x >> 2;
  const int r0  = (blockIdx.x & 3) << 6;

  {
    const float4* Xs = reinterpret_cast<const float4*>(X + ((size_t)b * S_ + r0) * D_);
#pragma unroll
    for (int it = 0; it < 8; ++it) {
      int i = it * 256 + tid;
      float4 v = Xs[i];
      int row = i >> 5, col = (i & 31) << 2;
      *reinterpret_cast<float4*>(&xt[row][col]) = v;
    }
  }
  __syncthreads();

  const int l = tid & 63;
  const int g = __builtin_amdgcn_readfirstlane(tid >> 6);
  const int k0 = (g < 2) ? 7 * g : 6 * g + 2;
  const int kn = (g < 2) ? 7 : 6;

  float acc[7][4];
#pragma unroll
  for (int kk = 0; kk < 7; ++kk)
#pragma unroll
    for (int c = 0; c < 4; ++c) acc[kk][c] = 0.f;

#pragma unroll
  for (int dc = 0; dc < 16; ++dc) {
    float4 a0 = *reinterpret_cast<const float4*>(&xt[l][dc * 8]);
    float4 a1 = *reinterpret_cast<const float4*>(&xt[l][dc * 8 + 4]);
    float xv[8] = {a0.x, a0.y, a0.z, a0.w, a1.x, a1.y, a1.z, a1.w};
#pragma unroll
    for (int kk = 0; kk < 7; ++kk) {
      int k = k0 + kk; k = (k > K_ - 1) ? (K_ - 1) : k;
      const float* wr = W + k * D_ + dc * 8;
#pragma unroll
      for (int dd = 0; dd < 8; ++dd)
        acc[kk][dd & 3] = fmaf(xv[dd], wr[dd], acc[kk][dd & 3]);
    }
  }

  float* eb = E + ((size_t)b * S_ + r0 + l) * K_ + k0;
#pragma unroll
  for (int kk = 0; kk < 7; ++kk)
    if (kk < kn)
      eb[kk] = (acc[kk][0] + acc[kk][1]) + (acc[kk][2] + acc[kk][3]);
}

// -------- Kernel 2: Viterbi, 8 chains per block (8 waves -> 2 waves/SIMD) ------------
__global__ __launch_bounds__(64 * CPB, 2) void viterbi_kernel(
    const float* __restrict__ E, const float* __restrict__ Tr, int* __restrict__ out)
{
  __shared__ unsigned char bp[CPB][K_][260];     // 54.1 KB
  __shared__ unsigned char spec[CPB][K_][132];   // 27.5 KB
  __shared__ int path_s[CPB][S_];                //  8.2 KB

  const int tid  = threadIdx.x;
  const int lane = tid & 63;
  const int w    = tid >> 6;                 // chain within block
  const int b    = blockIdx.x * CPB + w;
  const int j    = lane & 31;                // state column, valid < 26
  const int h    = lane >> 5;                // i-half: [0,13) / [13,26)
  const int jc   = (j < K_) ? j : (K_ - 1);
  const int srcbase = 13 * h;

  // per-lane transition slice: tch[i] = Tr[i + 13*h][jc]
  float tch[13];
#pragma unroll
  for (int i = 0; i < 13; ++i) tch[i] = Tr[(i + 13 * h) * K_ + jc];

  const float* eb = E + (size_t)b * (S_ * K_);

  float delta = eb[jc];                      // t = 0
  float ev1 = eb[K_ + jc];                   // row t=1
  float ev2 = eb[2 * K_ + jc];               // row t=2

  for (int t = 1; t < S_; ++t) {
    float ev = ev1; ev1 = ev2;
    if (t + 2 < S_) ev2 = eb[(size_t)(t + 2) * K_ + jc];   // dist-2 prefetch

    float v[13]; int id[13];
#pragma unroll
    for (int i = 0; i < 13; ++i) {
      v[i]  = __shfl(delta, srcbase + i, 64) + tch[i];     // one bpermute cluster
      id[i] = srcbase + i;
    }
    // ordered tournament (left/lower index wins ties -> first-max, jnp.argmax)
#pragma unroll
    for (int ww = 1; ww < 16; ww <<= 1) {
#pragma unroll
      for (int i = 0; i + ww < 13; i += 2 * ww) {
        bool g = v[i + ww] > v[i];
        v[i]  = g ? v[i + ww] : v[i];
        id[i] = g ? id[i + ww] : id[i];
      }
    }
    // cross-half merge; lower-i half is the tie-preferred side
    float ov = __shfl_xor(v[0], 32, 64);
    int   oi = __shfl_xor(id[0], 32, 64);
    float lv = (h == 0) ? v[0] : ov;   int li  = (h == 0) ? id[0] : oi;
    float hv = (h == 0) ? ov   : v[0]; int hi_ = (h == 0) ? oi   : id[0];
    bool gt = hv > lv;
    float best = gt ? hv : lv;
    int   bpi  = gt ? hi_ : li;
    if (h == 0 && j < K_) bp[w][j][t] = (unsigned char)bpi;
    delta = best + ev;                       // same op order as reference
  }

  // final first-argmax over delta[0..25]
  float bf = __shfl(delta, 0, 64); int last = 0;
#pragma unroll
  for (int i = 1; i < K_; ++i) {
    float s = __shfl(delta, i, 64);
    bool g = s > bf;
    bf = g ? s : bf;
    last = g ? i : last;
  }

  __syncthreads();

  // backtrack: real chain (lane 63) t=255..129 concurrent with 26 speculative
  // chains (lanes 0..25) covering t=128..1 for every possible state@128.
  {
    int c = (lane < K_) ? lane : last;
    for (int k = 0; k < 128; ++k) {
      int t = (lane < K_) ? (128 - k) : (255 - k);
      bool act = (lane < K_) || (lane == 63 && k <= 126);
      if (act) {
        c = bp[w][c][t];
        if (lane < K_) spec[w][lane][t - 1] = (unsigned char)c;
        else if (t >= 129) path_s[w][t - 1] = c;   // covers 128..254
      }
    }
  }
  __syncthreads();

  {
    int sstar = path_s[w][128];              // realized state at t=128
#pragma unroll
    for (int q = 0; q < 2; ++q) {
      int t = q * 64 + lane;
      path_s[w][t] = (int)spec[w][sstar][t];
    }
    if (lane == 0) path_s[w][S_ - 1] = last;
  }
  __syncthreads();

  int* o = out + (size_t)b * S_;
#pragma unroll
  for (int q = 0; q < 4; ++q) o[q * 64 + lane] = path_s[w][q * 64 + lane];
}

extern "C" void kernel_launch(void* const* d_in, const int* in_sizes, int n_in,
                              void* d_out, int out_size, void* d_ws, size_t ws_size,
                              hipStream_t stream) {
  (void)in_sizes; (void)n_in; (void)out_size; (void)ws_size;
  const float* X  = (const float*)d_in[0];
  const float* W  = (const float*)d_in[1];
  const float* Tr = (const float*)d_in[2];
  float* E = (float*)d_ws;             // needs B*S*K*4 = 27,262,976 B of scratch
  int* outp = (int*)d_out;

  emis_kernel<<<B_ * 4, 256, 0, stream>>>(X, W, E);
  viterbi_kernel<<<B_ / CPB, 64 * CPB, 0, stream>>>(E, Tr, outp);
}

// Round 5
// 210.471 us; speedup vs baseline: 5.5361x; 1.8616x over previous
//
#include <hip/hip_runtime.h>

#define B_ 1024
#define S_ 256
#define D_ 128
#define K_ 26

// ---------------- Kernel 1: emissions E[b][t][k] = dot(X[b][t], W[k]) ----------------
__global__ __launch_bounds__(256, 2) void emis_kernel(
    const float* __restrict__ X, const float* __restrict__ W, float* __restrict__ E)
{
  __shared__ float xt[64][132];
  const int tid = threadIdx.x;
  const int b   = blockIdx.x >> 2;
  const int r0  = (blockIdx.x & 3) << 6;

  {
    const float4* Xs = reinterpret_cast<const float4*>(X + ((size_t)b * S_ + r0) * D_);
#pragma unroll
    for (int it = 0; it < 8; ++it) {
      int i = it * 256 + tid;
      float4 v = Xs[i];
      int row = i >> 5, col = (i & 31) << 2;
      *reinterpret_cast<float4*>(&xt[row][col]) = v;
    }
  }
  __syncthreads();

  const int l = tid & 63;
  const int g = __builtin_amdgcn_readfirstlane(tid >> 6);
  const int k0 = (g < 2) ? 7 * g : 6 * g + 2;
  const int kn = (g < 2) ? 7 : 6;

  float acc[7][4];
#pragma unroll
  for (int kk = 0; kk < 7; ++kk)
#pragma unroll
    for (int c = 0; c < 4; ++c) acc[kk][c] = 0.f;

#pragma unroll
  for (int dc = 0; dc < 16; ++dc) {
    float4 a0 = *reinterpret_cast<const float4*>(&xt[l][dc * 8]);
    float4 a1 = *reinterpret_cast<const float4*>(&xt[l][dc * 8 + 4]);
    float xv[8] = {a0.x, a0.y, a0.z, a0.w, a1.x, a1.y, a1.z, a1.w};
#pragma unroll
    for (int kk = 0; kk < 7; ++kk) {
      int k = k0 + kk; k = (k > K_ - 1) ? (K_ - 1) : k;
      const float* wr = W + k * D_ + dc * 8;
#pragma unroll
      for (int dd = 0; dd < 8; ++dd)
        acc[kk][dd & 3] = fmaf(xv[dd], wr[dd], acc[kk][dd & 3]);
    }
  }

  float* eb = E + ((size_t)b * S_ + r0 + l) * K_ + k0;
#pragma unroll
  for (int kk = 0; kk < 7; ++kk)
    if (kk < kn)
      eb[kk] = (acc[kk][0] + acc[kk][1]) + (acc[kk][2] + acc[kk][3]);
}

// -------- Kernel 2: Viterbi. Lane j = state j; full tc column; max3 value tree. ------
__device__ __forceinline__ float bcast(float x, int srcLane) {
  return __int_as_float(__builtin_amdgcn_ds_bpermute(srcLane << 2, __float_as_int(x)));
}

__global__ __launch_bounds__(64, 1) void viterbi_kernel(
    const float* __restrict__ E, const float* __restrict__ Tr, int* __restrict__ out)
{
  __shared__ unsigned char bp[K_][260];
  __shared__ unsigned char spec[K_][132];
  __shared__ int path_s[S_];

  const int lane = threadIdx.x;
  const int jc   = (lane < K_) ? lane : (K_ - 1);
  const int b    = blockIdx.x;

  // full transition column for my state: tc[i] = Tr[i][jc]
  float tc[K_];
#pragma unroll
  for (int i = 0; i < K_; ++i) tc[i] = Tr[i * K_ + jc];

  const float* eb = E + (size_t)b * (S_ * K_);

  float delta = eb[jc];                    // t = 0
  float ev1 = eb[K_ + jc];
  float ev2 = eb[2 * K_ + jc];

  for (int t = 1; t < S_; ++t) {
    float ev = ev1; ev1 = ev2;
    if (t + 2 < S_) ev2 = eb[(size_t)(t + 2) * K_ + jc];   // dist-2 prefetch (L2-resident)

    // one LDS-latency broadcast of all 26 deltas (independent bpermutes)
    float v[K_];
#pragma unroll
    for (int i = 0; i < K_; ++i) v[i] = bcast(delta, i) + tc[i];

    // ---- value path (critical): max3 tree, depth 3 ----
    float m[9];
#pragma unroll
    for (int i = 0; i < 8; ++i) m[i] = fmaxf(fmaxf(v[3*i], v[3*i+1]), v[3*i+2]);
    m[8] = fmaxf(v[24], v[25]);
    float n0 = fmaxf(fmaxf(m[0], m[1]), m[2]);
    float n1 = fmaxf(fmaxf(m[3], m[4]), m[5]);
    float n2 = fmaxf(fmaxf(m[6], m[7]), m[8]);
    float best = fmaxf(fmaxf(n0, n1), n2);

    // ---- argmax path (off critical path): first i with v[i]==best ----
    int c[K_];
#pragma unroll
    for (int i = 0; i < K_; ++i) c[i] = (v[i] == best) ? i : 63;
    int q[9];
#pragma unroll
    for (int i = 0; i < 8; ++i) { int a = c[3*i] < c[3*i+1] ? c[3*i] : c[3*i+1]; q[i] = a < c[3*i+2] ? a : c[3*i+2]; }
    q[8] = c[24] < c[25] ? c[24] : c[25];
    int r0 = q[0] < q[1] ? q[0] : q[1]; r0 = r0 < q[2] ? r0 : q[2];
    int r1 = q[3] < q[4] ? q[3] : q[4]; r1 = r1 < q[5] ? r1 : q[5];
    int r2 = q[6] < q[7] ? q[6] : q[7]; r2 = r2 < q[8] ? r2 : q[8];
    int idx = r0 < r1 ? r0 : r1; idx = idx < r2 ? idx : r2;

    if (lane < K_) bp[lane][t] = (unsigned char)idx;
    delta = best + ev;                     // same op order as reference
  }

  // final first-argmax over delta[0..25] (uniform on all lanes)
  int last;
  {
    float v[K_];
#pragma unroll
    for (int i = 0; i < K_; ++i) v[i] = bcast(delta, i);
    float m[9];
#pragma unroll
    for (int i = 0; i < 8; ++i) m[i] = fmaxf(fmaxf(v[3*i], v[3*i+1]), v[3*i+2]);
    m[8] = fmaxf(v[24], v[25]);
    float n0 = fmaxf(fmaxf(m[0], m[1]), m[2]);
    float n1 = fmaxf(fmaxf(m[3], m[4]), m[5]);
    float n2 = fmaxf(fmaxf(m[6], m[7]), m[8]);
    float best = fmaxf(fmaxf(n0, n1), n2);
    int c[K_];
#pragma unroll
    for (int i = 0; i < K_; ++i) c[i] = (v[i] == best) ? i : 63;
    int q[9];
#pragma unroll
    for (int i = 0; i < 8; ++i) { int a = c[3*i] < c[3*i+1] ? c[3*i] : c[3*i+1]; q[i] = a < c[3*i+2] ? a : c[3*i+2]; }
    q[8] = c[24] < c[25] ? c[24] : c[25];
    int r0 = q[0] < q[1] ? q[0] : q[1]; r0 = r0 < q[2] ? r0 : q[2];
    int r1 = q[3] < q[4] ? q[3] : q[4]; r1 = r1 < q[5] ? r1 : q[5];
    int r2 = q[6] < q[7] ? q[6] : q[7]; r2 = r2 < q[8] ? r2 : q[8];
    last = r0 < r1 ? r0 : r1; last = last < r2 ? last : r2;
  }

  __syncthreads();

  // backtrack: real chain (lane 63) t=255..129 concurrent with 26 speculative
  // chains (lanes 0..25) covering t=128..1 for every possible state@128.
  {
    int c = (lane < K_) ? lane : last;
    for (int k = 0; k < 128; ++k) {
      int t = (lane < K_) ? (128 - k) : (255 - k);
      bool act = (lane < K_) || (lane == 63 && k <= 126);
      if (act) {
        c = bp[c][t];
        if (lane < K_) spec[lane][t - 1] = (unsigned char)c;
        else if (t >= 129) path_s[t - 1] = c;   // covers 128..254
      }
    }
  }
  __syncthreads();

  {
    int sstar = path_s[128];
#pragma unroll
    for (int q2 = 0; q2 < 2; ++q2) {
      int t = q2 * 64 + lane;
      path_s[t] = (int)spec[sstar][t];
    }
    if (lane == 0) path_s[S_ - 1] = last;
  }
  __syncthreads();

  int* o = out + (size_t)b * S_;
#pragma unroll
  for (int q2 = 0; q2 < 4; ++q2) o[q2 * 64 + lane] = path_s[q2 * 64 + lane];
}

extern "C" void kernel_launch(void* const* d_in, const int* in_sizes, int n_in,
                              void* d_out, int out_size, void* d_ws, size_t ws_size,
                              hipStream_t stream) {
  (void)in_sizes; (void)n_in; (void)out_size; (void)ws_size;
  const float* X  = (const float*)d_in[0];
  const float* W  = (const float*)d_in[1];
  const float* Tr = (const float*)d_in[2];
  float* E = (float*)d_ws;             // needs B*S*K*4 = 27,262,976 B of scratch
  int* outp = (int*)d_out;

  emis_kernel<<<B_ * 4, 256, 0, stream>>>(X, W, E);
  viterbi_kernel<<<B_, 64, 0, stream>>>(E, Tr, outp);
}